// Round 3
// baseline (347.704 us; speedup 1.0000x reference)
//
#include <hip/hip_runtime.h>

typedef _Float16 f16;
typedef _Float16 f16x8 __attribute__((ext_vector_type(8)));
typedef float    f32x4 __attribute__((ext_vector_type(4)));

#define MFMA16(A, B, C) __builtin_amdgcn_mfma_f32_16x16x32_f16((A), (B), (C), 0, 0, 0)

// Workspace layout (bytes).
static constexpr size_t OFF_XH  = 0;                       // X fp16      [8192][512]  8 MB
static constexpr size_t OFF_WQT = 8388608;                 // Wq^T (scaled) fp16 [512][512]
static constexpr size_t OFF_WKT = OFF_WQT + 524288;        // (WQT..WVT contiguous = QKV B^T [1536][512])
static constexpr size_t OFF_WVT = OFF_WKT + 524288;
static constexpr size_t OFF_WOT = OFF_WVT + 524288;
static constexpr size_t OFF_QH  = OFF_WOT + 524288;        // Q fp16 [8192][512] (pre-scaled by 0.125*log2e)
static constexpr size_t OFF_KH  = OFF_QH + 8388608;        // K fp16 [8192][512]
static constexpr size_t OFF_VT  = OFF_KH + 8388608;        // V^T fp16 [4][8][64][2048]
static constexpr size_t OFF_A2  = OFF_VT + 8388608;        // attn out fp16 [8192][512]

// log2(e)*0.125 folded into Wq;  FIX = 8*log2(e) subtracted via MFMA C-init.
#define QSCALE 0.18033688011112042f
#define NEGFIX -11.541560327111708f

// ---------------- convert x: fp32 -> fp16, 8 elems/thread ----------------
__global__ void k_cvt_x(const float* __restrict__ x, f16* __restrict__ xh) {
  int i = blockIdx.x * blockDim.x + threadIdx.x;
  const float4* p = (const float4*)x + (size_t)i * 2;
  float4 a = p[0], b = p[1];
  f16x8 o = { (f16)a.x, (f16)a.y, (f16)a.z, (f16)a.w,
              (f16)b.x, (f16)b.y, (f16)b.z, (f16)b.w };
  *((f16x8*)xh + i) = o;
}

// ---- transpose+convert all 4 weights (z picks which); Wq gets QSCALE folded ----
__global__ void k_cvt_w4(const float* __restrict__ w0, const float* __restrict__ w1,
                         const float* __restrict__ w2, const float* __restrict__ w3,
                         f16* __restrict__ dst) {
  __shared__ float tile[32][33];
  const int z = blockIdx.z;
  const float* w = (z == 0) ? w0 : (z == 1) ? w1 : (z == 2) ? w2 : w3;
  const float sc = (z == 0) ? QSCALE : 1.0f;
  f16* wt = dst + (size_t)z * 262144;
  int tx = threadIdx.x & 31, ty = threadIdx.x >> 5;
  int bx = blockIdx.x, by = blockIdx.y;
#pragma unroll
  for (int i = 0; i < 32; i += 8)
    tile[ty + i][tx] = w[(size_t)(by * 32 + ty + i) * 512 + bx * 32 + tx];
  __syncthreads();
#pragma unroll
  for (int i = 0; i < 32; i += 8)
    wt[(size_t)(bx * 32 + ty + i) * 512 + by * 32 + tx] = (f16)(tile[tx][ty + i] * sc);
}

// ---------------- 128xBN-tile fp16 MFMA GEMM, K=512, BK=64 ----------------
// A: [M][512] fp16.  Bt: [*][512] fp16 = B^T.
// MODE 2: C fp32 row-major [M][512] + bias   (O0)
// MODE 3: fused QKV: col seg 0->Q fp16 (O0), 1->K fp16 (O1), 2->V^T scatter (O2)
template <int MODE, int BN>
__global__ __launch_bounds__(256, 3)
void k_gemm(const f16* __restrict__ A, const f16* __restrict__ Bt,
            void* __restrict__ O0, void* __restrict__ O1, void* __restrict__ O2,
            const float* __restrict__ bias) {
  constexpr int NF = BN / 32;   // n-frags per wave
  constexpr int PB = BN / 32;   // B-stage uint4 chunks per thread
  __shared__ __align__(16) f16 sA[128 * 64];
  __shared__ __align__(16) f16 sB[BN * 64];
  const int t = threadIdx.x;
  const int lane = t & 63, w = t >> 6;
  const int wr = w >> 1, wc = w & 1;
  const int l15 = lane & 15, l4 = lane >> 4;
  const int row0 = blockIdx.y * 128;
  const int col0 = blockIdx.x * BN;

  f32x4 acc[4][NF] = {};
  uint4 ra[4], rb[PB];

  auto load_tiles = [&](int kt) {
#pragma unroll
    for (int p = 0; p < 4; ++p) {
      int lb = p * 4096 + t * 16;
      int r = lb >> 7, cb = lb & 127;
      ra[p] = *(const uint4*)((const char*)A + ((size_t)(row0 + r) * 512 + kt) * 2 + cb);
    }
#pragma unroll
    for (int p = 0; p < PB; ++p) {
      int lb = p * 4096 + t * 16;
      int r = lb >> 7, cb = lb & 127;
      rb[p] = *(const uint4*)((const char*)Bt + ((size_t)(col0 + r) * 512 + kt) * 2 + cb);
    }
  };

  load_tiles(0);
  for (int kt = 0; kt < 512; kt += 64) {
    __syncthreads();                         // prior tile fully consumed
#pragma unroll
    for (int p = 0; p < 4; ++p) {
      int lb = p * 4096 + t * 16;
      int pb = lb ^ (((lb >> 7) & 7) << 4);  // XOR swizzle
      *(uint4*)((char*)sA + pb) = ra[p];
    }
#pragma unroll
    for (int p = 0; p < PB; ++p) {
      int lb = p * 4096 + t * 16;
      int pb = lb ^ (((lb >> 7) & 7) << 4);
      *(uint4*)((char*)sB + pb) = rb[p];
    }
    __syncthreads();                         // staging visible
    if (kt < 448) load_tiles(kt + 64);       // issue AFTER bar2: latency hides under compute
#pragma unroll
    for (int kb = 0; kb < 2; ++kb) {
      f16x8 af[4], bf[NF];
#pragma unroll
      for (int m = 0; m < 4; ++m) {
        int r = wr * 64 + m * 16 + l15;
        int lb = r * 128 + kb * 64 + l4 * 16;
        af[m] = *(const f16x8*)((const char*)sA + (lb ^ ((r & 7) << 4)));
      }
#pragma unroll
      for (int n = 0; n < NF; ++n) {
        int r = wc * (BN / 2) + n * 16 + l15;
        int lb = r * 128 + kb * 64 + l4 * 16;
        bf[n] = *(const f16x8*)((const char*)sB + (lb ^ ((r & 7) << 4)));
      }
#pragma unroll
      for (int m = 0; m < 4; ++m)
#pragma unroll
        for (int n = 0; n < NF; ++n)
          acc[m][n] = MFMA16(af[m], bf[n], acc[m][n]);
    }
  }

  // epilogue; C frag: col = lane&15, row = (lane>>4)*4 + reg
#pragma unroll
  for (int m = 0; m < 4; ++m) {
#pragma unroll
    for (int n = 0; n < NF; ++n) {
      int gr = row0 + wr * 64 + m * 16 + l4 * 4;
      int gc = col0 + wc * (BN / 2) + n * 16 + l15;
      if (MODE == 2) {
        float* C = (float*)O0;
        float bv = bias[gc];
#pragma unroll
        for (int rr = 0; rr < 4; ++rr)
          C[(size_t)(gr + rr) * 512 + gc] = acc[m][n][rr] + bv;
      } else {                               // MODE 3
        int seg = col0 >> 9;                 // uniform per block
        int lc = gc & 511;
        if (seg < 2) {
          f16* C = (f16*)(seg == 0 ? O0 : O1);
#pragma unroll
          for (int rr = 0; rr < 4; ++rr)
            C[(size_t)(gr + rr) * 512 + lc] = (f16)acc[m][n][rr];
        } else {
          f16* C = (f16*)O2;
          int hh = lc >> 6, dd = lc & 63;
          int bb = gr >> 11, ns = gr & 2047;
          union { uint2 u2; f16 v[4]; } pk;
#pragma unroll
          for (int rr = 0; rr < 4; ++rr) pk.v[rr] = (f16)acc[m][n][rr];
          *(uint2*)(C + (size_t)((bb * 8 + hh) * 64 + dd) * 2048 + ns) = pk.u2;
        }
      }
    }
  }
}

// ---------------- flash attention, fixed-max softmax, denom via MFMA ----------------
// Q pre-scaled by 0.125*log2e.  P = exp2(s + NEGFIX)  (NEGFIX folded into MFMA C-init).
// Denominator = P @ ones  via 2 extra MFMAs/tile (no shuffles, no rescale).
__global__ __launch_bounds__(256, 4)
void k_attn(const f16* __restrict__ Q, const f16* __restrict__ K,
            const f16* __restrict__ Vt, const int* __restrict__ mask_k,
            const int* __restrict__ mask_q, f16* __restrict__ A2) {
  __shared__ __align__(16) f16 sK[64 * 64];   // [j][d], swizzled
  __shared__ __align__(16) f16 sV[64 * 64];   // [d][j], swizzled
  __shared__ __align__(16) f16 sP[4][16][72]; // per-wave P (no cross-wave barrier needed)
  const int t = threadIdx.x, lane = t & 63, w = t >> 6;
  const int l15 = lane & 15, l4 = lane >> 4;
  const int bh = blockIdx.y, b = bh >> 3, h = bh & 7;
  const int q0 = blockIdx.x * 64 + w * 16;

  f16x8 qa[2];
  {
    const f16* qb = Q + (size_t)(b * 2048 + q0 + l15) * 512 + h * 64 + l4 * 8;
    qa[0] = *(const f16x8*)qb;
    qa[1] = *(const f16x8*)(qb + 32);
  }
  int mqi[4];
#pragma unroll
  for (int rr = 0; rr < 4; ++rr)
    mqi[rr] = mask_q[b * 2048 + q0 + l4 * 4 + rr];

  const f16x8 onesv = { (f16)1.f, (f16)1.f, (f16)1.f, (f16)1.f,
                        (f16)1.f, (f16)1.f, (f16)1.f, (f16)1.f };
  f32x4 o[4] = {};
  f32x4 oex = {};
  uint4 vkr[2], vvr[2];

  auto stage_load = [&](int kv) {
#pragma unroll
    for (int p = 0; p < 2; ++p) {
      int lb = p * 4096 + t * 16;
      int r = lb >> 7, cb = lb & 127;
      vkr[p] = *(const uint4*)((const char*)K +
                 ((size_t)(b * 2048 + kv + r) * 512 + h * 64) * 2 + cb);
      vvr[p] = *(const uint4*)((const char*)Vt +
                 ((size_t)((b * 8 + h) * 64 + r) * 2048 + kv) * 2 + cb);
    }
  };

  stage_load(0);
  for (int kv = 0; kv < 2048; kv += 64) {
    __syncthreads();                         // prior tile fully consumed
#pragma unroll
    for (int p = 0; p < 2; ++p) {
      int lb = p * 4096 + t * 16;
      int pb = lb ^ (((lb >> 7) & 7) << 4);
      *(uint4*)((char*)sK + pb) = vkr[p];
      *(uint4*)((char*)sV + pb) = vvr[p];
    }
    __syncthreads();                         // staging visible
    if (kv < 1984) stage_load(kv + 64);      // issue AFTER bar2

    int mk[4];
#pragma unroll
    for (int jf = 0; jf < 4; ++jf)
      mk[jf] = mask_k[b * 2048 + kv + jf * 16 + l15];

    // S = Q K^T + NEGFIX   (16 x 64 per wave)
    f32x4 s[4];
#pragma unroll
    for (int jf = 0; jf < 4; ++jf) {
      int r = jf * 16 + l15;
      int base = r * 128 + l4 * 16;
      f16x8 b0 = *(const f16x8*)((const char*)sK + (base ^ ((r & 7) << 4)));
      f16x8 b1 = *(const f16x8*)((const char*)sK + ((base + 64) ^ ((r & 7) << 4)));
      f32x4 z = { NEGFIX, NEGFIX, NEGFIX, NEGFIX };
      z = MFMA16(qa[0], b0, z);
      z = MFMA16(qa[1], b1, z);
      s[jf] = z;
    }
    // fixed-max softmax numerator: p = exp2(masked s); no reductions.
#pragma unroll
    for (int jf = 0; jf < 4; ++jf)
#pragma unroll
      for (int rr = 0; rr < 4; ++rr) {
        float sv = s[jf][rr];
        sv = mk[jf] ? sv : -1000.0f;        // masked key -> p = 0
        sv = mqi[rr] ? sv : -8.0f;          // masked q row -> uniform p
        float p = __builtin_amdgcn_exp2f(sv);
        sP[w][l4 * 4 + rr][jf * 16 + l15] = (f16)p;
      }
    // O += P V ; denom += P 1   (sP is wave-private: no barrier)
#pragma unroll
    for (int kb = 0; kb < 2; ++kb) {
      f16x8 pa = *(const f16x8*)&sP[w][l15][kb * 32 + l4 * 8];
      oex = MFMA16(pa, onesv, oex);
#pragma unroll
      for (int df = 0; df < 4; ++df) {
        int r = df * 16 + l15;
        int base = r * 128 + kb * 64 + l4 * 16;
        f16x8 bv = *(const f16x8*)((const char*)sV + (base ^ ((r & 7) << 4)));
        o[df] = MFMA16(pa, bv, o[df]);
      }
    }
  }

  float inv[4];
#pragma unroll
  for (int rr = 0; rr < 4; ++rr) inv[rr] = 1.0f / oex[rr];
#pragma unroll
  for (int df = 0; df < 4; ++df)
#pragma unroll
    for (int rr = 0; rr < 4; ++rr)
      A2[(size_t)(b * 2048 + q0 + l4 * 4 + rr) * 512 + h * 64 + df * 16 + l15] =
          (f16)(o[df][rr] * inv[rr]);
}

extern "C" void kernel_launch(void* const* d_in, const int* in_sizes, int n_in,
                              void* d_out, int out_size, void* d_ws, size_t ws_size,
                              hipStream_t stream) {
  (void)in_sizes; (void)n_in; (void)out_size; (void)ws_size;
  const float* x   = (const float*)d_in[0];
  const float* Wq  = (const float*)d_in[1];
  const float* Wk  = (const float*)d_in[2];
  const float* Wv  = (const float*)d_in[3];
  const float* Wo  = (const float*)d_in[4];
  const float* bo  = (const float*)d_in[5];
  const int* mask_k = (const int*)d_in[6];
  const int* mask_q = (const int*)d_in[7];
  float* out = (float*)d_out;
  char* ws = (char*)d_ws;

  f16* Xh   = (f16*)(ws + OFF_XH);
  f16* Wqkv = (f16*)(ws + OFF_WQT);   // [1536][512] stacked
  f16* Wot  = (f16*)(ws + OFF_WOT);
  f16* Qh   = (f16*)(ws + OFF_QH);
  f16* Kh   = (f16*)(ws + OFF_KH);
  f16* Vt   = (f16*)(ws + OFF_VT);
  f16* A2   = (f16*)(ws + OFF_A2);

  k_cvt_x<<<2048, 256, 0, stream>>>(x, Xh);
  k_cvt_w4<<<dim3(16, 16, 4), 256, 0, stream>>>(Wq, Wk, Wv, Wo, Wqkv);

  k_gemm<3, 128><<<dim3(12, 64), 256, 0, stream>>>(Xh, Wqkv, Qh, Kh, Vt, nullptr);

  k_attn<<<dim3(32, 32), 256, 0, stream>>>(Qh, Kh, Vt, mask_k, mask_q, A2);

  k_gemm<2, 64><<<dim3(8, 64), 256, 0, stream>>>(A2, Wot, out, nullptr, nullptr, bo);
}

// Round 4
// 210.022 us; speedup vs baseline: 1.6556x; 1.6556x over previous
//
#include <hip/hip_runtime.h>

typedef _Float16 f16;
typedef _Float16 f16x8 __attribute__((ext_vector_type(8)));
typedef float    f32x4 __attribute__((ext_vector_type(4)));

#define MFMA16(A, B, C) __builtin_amdgcn_mfma_f32_16x16x32_f16((A), (B), (C), 0, 0, 0)

// async 16B global->LDS (DMA, no VGPR round-trip). dest is wave-uniform base;
// HW adds lane*16. Source address is per-lane.
__device__ __forceinline__ void gl_lds16(const void* g, void* l) {
  __builtin_amdgcn_global_load_lds(
      (const __attribute__((address_space(1))) void*)g,
      (__attribute__((address_space(3))) void*)l, 16, 0, 0);
}

// Workspace layout (bytes).
static constexpr size_t OFF_XH  = 0;                       // X fp16 [8192][512]
static constexpr size_t OFF_WQT = 8388608;                 // QKV B^T stacked [1536][512]
static constexpr size_t OFF_WOT = OFF_WQT + 3 * 524288;
static constexpr size_t OFF_QH  = OFF_WOT + 524288;        // Q fp16 [8192][512] (pre-scaled)
static constexpr size_t OFF_KH  = OFF_QH + 8388608;        // K fp16 [8192][512]
static constexpr size_t OFF_VT  = OFF_KH + 8388608;        // V^T fp16 [4][8][64][2048]
static constexpr size_t OFF_A2  = OFF_VT + 8388608;        // attn out fp16 [8192][512]

// log2(e)*0.125 folded into Wq;  8*log2(e) subtracted via MFMA C-init.
#define QSCALE 0.18033688011112042f
#define NEGFIX -11.541560327111708f

// ---------------- convert x: fp32 -> fp16, 8 elems/thread ----------------
__global__ void k_cvt_x(const float* __restrict__ x, f16* __restrict__ xh) {
  int i = blockIdx.x * blockDim.x + threadIdx.x;
  const float4* p = (const float4*)x + (size_t)i * 2;
  float4 a = p[0], b = p[1];
  f16x8 o = { (f16)a.x, (f16)a.y, (f16)a.z, (f16)a.w,
              (f16)b.x, (f16)b.y, (f16)b.z, (f16)b.w };
  *((f16x8*)xh + i) = o;
}

// ---- transpose+convert all 4 weights (z picks which); Wq gets QSCALE folded ----
__global__ void k_cvt_w4(const float* __restrict__ w0, const float* __restrict__ w1,
                         const float* __restrict__ w2, const float* __restrict__ w3,
                         f16* __restrict__ dst) {
  __shared__ float tile[32][33];
  const int z = blockIdx.z;
  const float* w = (z == 0) ? w0 : (z == 1) ? w1 : (z == 2) ? w2 : w3;
  const float sc = (z == 0) ? QSCALE : 1.0f;
  f16* wt = dst + (size_t)z * 262144;
  int tx = threadIdx.x & 31, ty = threadIdx.x >> 5;
  int bx = blockIdx.x, by = blockIdx.y;
#pragma unroll
  for (int i = 0; i < 32; i += 8)
    tile[ty + i][tx] = w[(size_t)(by * 32 + ty + i) * 512 + bx * 32 + tx];
  __syncthreads();
#pragma unroll
  for (int i = 0; i < 32; i += 8)
    wt[(size_t)(bx * 32 + ty + i) * 512 + by * 32 + tx] = (f16)(tile[tx][ty + i] * sc);
}

// ---------------- 128xBN-tile fp16 MFMA GEMM, K=512, BK=64, m97 structure --------
// A: [M][512] fp16.  Bt: [*][512] fp16 = B^T.
// MODE 2: C fp32 row-major [M][512] + bias   (O0)
// MODE 3: fused QKV: col seg 0->Q fp16 (O0), 1->K fp16 (O1), 2->V^T scatter (O2)
template <int MODE, int BN>
__global__ __launch_bounds__(256, 3)
void k_gemm(const f16* __restrict__ A, const f16* __restrict__ Bt,
            void* __restrict__ O0, void* __restrict__ O1, void* __restrict__ O2,
            const float* __restrict__ bias) {
  constexpr int NF = BN / 32;                       // n-frags per wave
  constexpr int PB = BN / 32;                       // B 4KB-issues
  constexpr int SM_STAGE  = 16384 + BN * 128;       // sA + sB bytes
  constexpr int SM_BOUNCE = (MODE == 3) ? 128 * 136 * 2 : 0;
  constexpr int SM = SM_STAGE > SM_BOUNCE ? SM_STAGE : SM_BOUNCE;
  __shared__ __align__(16) char smem[SM];
  f16* sA = (f16*)smem;                             // [128][64] swizzled
  f16* sB = (f16*)(smem + 16384);                   // [BN][64]  swizzled
  const int t = threadIdx.x;
  const int lane = t & 63, w = t >> 6;
  const int wr = w >> 1, wc = w & 1;
  const int l15 = lane & 15, l4 = lane >> 4;
  const int lr = lane >> 3, lc = lane & 7;          // staging row-within-8 / chunk
  const int row0 = blockIdx.y * 128;
  const int col0 = blockIdx.x * BN;

  f32x4 acc[4][NF] = {};

  for (int kt = 0; kt < 512; kt += 64) {
    __syncthreads();                                // all reads of prev tile done
#pragma unroll
    for (int p = 0; p < 4; ++p) {                   // A: 16KB = 4 issues
      int r = p * 32 + w * 8 + lr;
      gl_lds16((const char*)A + ((size_t)(row0 + r) * 512 + kt) * 2 + ((lc ^ (r & 7)) << 4),
               (char*)sA + p * 4096 + w * 1024);
    }
#pragma unroll
    for (int p = 0; p < PB; ++p) {                  // B
      int r = p * 32 + w * 8 + lr;
      gl_lds16((const char*)Bt + ((size_t)(col0 + r) * 512 + kt) * 2 + ((lc ^ (r & 7)) << 4),
               (char*)sB + p * 4096 + w * 1024);
    }
    __syncthreads();                                // drains vmcnt -> tile visible
#pragma unroll
    for (int kb = 0; kb < 2; ++kb) {
      f16x8 af[4], bf[NF];
#pragma unroll
      for (int m = 0; m < 4; ++m) {
        int r = wr * 64 + m * 16 + l15;
        int lb = r * 128 + kb * 64 + l4 * 16;
        af[m] = *(const f16x8*)((const char*)sA + (lb ^ ((r & 7) << 4)));
      }
#pragma unroll
      for (int n = 0; n < NF; ++n) {
        int r = wc * (BN / 2) + n * 16 + l15;
        int lb = r * 128 + kb * 64 + l4 * 16;
        bf[n] = *(const f16x8*)((const char*)sB + (lb ^ ((r & 7) << 4)));
      }
#pragma unroll
      for (int m = 0; m < 4; ++m)
#pragma unroll
        for (int n = 0; n < NF; ++n)
          acc[m][n] = MFMA16(af[m], bf[n], acc[m][n]);
    }
  }

  // ---- epilogue; C frag: col = lane&15, row = (lane>>4)*4 + reg ----
  if (MODE == 2) {
    // fp32 + bias, direct stores (64B contiguous per quarter-wave)
#pragma unroll
    for (int m = 0; m < 4; ++m)
#pragma unroll
      for (int n = 0; n < NF; ++n) {
        int gr = row0 + wr * 64 + m * 16 + l4 * 4;
        int gc = col0 + wc * (BN / 2) + n * 16 + l15;
        float* C = (float*)O0;
        float bv = bias[gc];
#pragma unroll
        for (int rr = 0; rr < 4; ++rr)
          C[(size_t)(gr + rr) * 512 + gc] = acc[m][n][rr] + bv;
      }
  } else {                                          // MODE 3
    int seg = col0 >> 9;                            // block-uniform
    if (seg < 2) {
      // LDS bounce -> coalesced 16B stores (fixes 2B-at-1KB-stride amplification)
      __syncthreads();                              // sA/sB reads done
      f16* bb = (f16*)smem;                         // [128][136]
#pragma unroll
      for (int m = 0; m < 4; ++m)
#pragma unroll
        for (int n = 0; n < NF; ++n) {
          int r = wr * 64 + m * 16 + l4 * 4;
          int c = wc * (BN / 2) + n * 16 + l15;
#pragma unroll
          for (int rr = 0; rr < 4; ++rr)
            bb[(r + rr) * 136 + c] = (f16)acc[m][n][rr];
        }
      __syncthreads();
      f16* C = (f16*)(seg == 0 ? O0 : O1);
      int cbase = col0 & 511;
#pragma unroll
      for (int i = 0; i < 8; ++i) {
        int idx = i * 256 + t;                      // 2048 x uint4
        int r = idx >> 4, c8 = (idx & 15) * 8;
        uint4 v = *(const uint4*)(bb + r * 136 + c8);
        *(uint4*)(C + (size_t)(row0 + r) * 512 + cbase + c8) = v;
      }
    } else {
      // V^T scatter: 4 consecutive tokens -> 8B-aligned uint2 along n
#pragma unroll
      for (int m = 0; m < 4; ++m)
#pragma unroll
        for (int n = 0; n < NF; ++n) {
          int gr = row0 + wr * 64 + m * 16 + l4 * 4;
          int lcol = (col0 & 511) + wc * (BN / 2) + n * 16 + l15;
          f16* C = (f16*)O2;
          int hh = lcol >> 6, dd = lcol & 63;
          int bb2 = gr >> 11, ns = gr & 2047;
          union { uint2 u2; f16 v[4]; } pk;
#pragma unroll
          for (int rr = 0; rr < 4; ++rr) pk.v[rr] = (f16)acc[m][n][rr];
          *(uint2*)(C + (size_t)((bb2 * 8 + hh) * 64 + dd) * 2048 + ns) = pk.u2;
        }
    }
  }
}

// ------------- flash attention: fixed-max softmax, denom via MFMA -------------
// Q pre-scaled by 0.125*log2e.  P = exp2(s + NEGFIX).  Denominator = P @ ones.
// K/V double-buffered in LDS via global_load_lds; ONE barrier per tile.
__global__ __launch_bounds__(256, 3)
void k_attn(const f16* __restrict__ Q, const f16* __restrict__ K,
            const f16* __restrict__ Vt, const int* __restrict__ mask_k,
            const int* __restrict__ mask_q, f16* __restrict__ A2) {
  __shared__ __align__(16) f16 sK[2][64 * 64];      // [j][d], swizzled
  __shared__ __align__(16) f16 sV[2][64 * 64];      // [d][j], swizzled
  __shared__ __align__(16) f16 sP[4][16][72];       // per-wave P
  const int t = threadIdx.x, lane = t & 63, w = t >> 6;
  const int l15 = lane & 15, l4 = lane >> 4;
  const int lr = lane >> 3, lc = lane & 7;
  const int bh = blockIdx.y, b = bh >> 3, h = bh & 7;
  const int q0 = blockIdx.x * 64 + w * 16;

  f16x8 qa[2];
  {
    const f16* qb = Q + (size_t)(b * 2048 + q0 + l15) * 512 + h * 64 + l4 * 8;
    qa[0] = *(const f16x8*)qb;
    qa[1] = *(const f16x8*)(qb + 32);
  }
  int mqi[4];
#pragma unroll
  for (int rr = 0; rr < 4; ++rr)
    mqi[rr] = mask_q[b * 2048 + q0 + l4 * 4 + rr];

  const f16x8 onesv = { (f16)1.f, (f16)1.f, (f16)1.f, (f16)1.f,
                        (f16)1.f, (f16)1.f, (f16)1.f, (f16)1.f };
  f32x4 o[4] = {};
  f32x4 oex = {};

  const char* Kbase  = (const char*)K + ((size_t)b * 2048 * 512 + h * 64) * 2;
  const char* VtBase = (const char*)Vt + ((size_t)(b * 8 + h) * 64) * 2048 * 2;

  auto stage = [&](int kv, int buf) {
#pragma unroll
    for (int p = 0; p < 2; ++p) {
      int r = p * 32 + w * 8 + lr;
      gl_lds16(Kbase + (size_t)(kv + r) * 1024 + ((lc ^ (r & 7)) << 4),
               (char*)&sK[buf][0] + p * 4096 + w * 1024);
      gl_lds16(VtBase + ((size_t)r * 2048 + kv) * 2 + ((lc ^ (r & 7)) << 4),
               (char*)&sV[buf][0] + p * 4096 + w * 1024);
    }
  };

  stage(0, 0);
  for (int it = 0; it < 32; ++it) {
    const int kv = it * 64, buf = it & 1;
    __syncthreads();                 // drains vmcnt: buf ready; buf^1 reads done
    if (it < 31) stage(kv + 64, buf ^ 1);   // hides under this tile's compute

    int mk[4];
#pragma unroll
    for (int jf = 0; jf < 4; ++jf)
      mk[jf] = mask_k[b * 2048 + kv + jf * 16 + l15];

    // S = Q K^T + NEGFIX   (16 x 64 per wave)
    f32x4 s[4];
#pragma unroll
    for (int jf = 0; jf < 4; ++jf) {
      int r = jf * 16 + l15;
      int base = r * 128 + l4 * 16;
      f16x8 b0 = *(const f16x8*)((const char*)&sK[buf][0] + (base ^ ((r & 7) << 4)));
      f16x8 b1 = *(const f16x8*)((const char*)&sK[buf][0] + ((base + 64) ^ ((r & 7) << 4)));
      f32x4 z = { NEGFIX, NEGFIX, NEGFIX, NEGFIX };
      z = MFMA16(qa[0], b0, z);
      z = MFMA16(qa[1], b1, z);
      s[jf] = z;
    }
    // fixed-max numerator: p = exp2(masked s); no reductions, no rescale.
#pragma unroll
    for (int jf = 0; jf < 4; ++jf)
#pragma unroll
      for (int rr = 0; rr < 4; ++rr) {
        float sv = s[jf][rr];
        sv = mk[jf] ? sv : -1000.0f;       // masked key -> p = 0
        sv = mqi[rr] ? sv : -8.0f;         // masked q row -> uniform p
        float p = __builtin_amdgcn_exp2f(sv);
        sP[w][l4 * 4 + rr][jf * 16 + l15] = (f16)p;
      }
    // O += P V ; denom += P 1   (sP wave-private: no barrier)
#pragma unroll
    for (int kb = 0; kb < 2; ++kb) {
      f16x8 pa = *(const f16x8*)&sP[w][l15][kb * 32 + l4 * 8];
      oex = MFMA16(pa, onesv, oex);
#pragma unroll
      for (int df = 0; df < 4; ++df) {
        int r = df * 16 + l15;
        int base = r * 128 + kb * 64 + l4 * 16;
        f16x8 bv = *(const f16x8*)((const char*)&sV[buf][0] + (base ^ ((r & 7) << 4)));
        o[df] = MFMA16(pa, bv, o[df]);
      }
    }
  }

  float inv[4];
#pragma unroll
  for (int rr = 0; rr < 4; ++rr) inv[rr] = 1.0f / oex[rr];
#pragma unroll
  for (int df = 0; df < 4; ++df)
#pragma unroll
    for (int rr = 0; rr < 4; ++rr)
      A2[(size_t)(b * 2048 + q0 + l4 * 4 + rr) * 512 + h * 64 + df * 16 + l15] =
          (f16)(o[df][rr] * inv[rr]);
}

extern "C" void kernel_launch(void* const* d_in, const int* in_sizes, int n_in,
                              void* d_out, int out_size, void* d_ws, size_t ws_size,
                              hipStream_t stream) {
  (void)in_sizes; (void)n_in; (void)out_size; (void)ws_size;
  const float* x   = (const float*)d_in[0];
  const float* Wq  = (const float*)d_in[1];
  const float* Wk  = (const float*)d_in[2];
  const float* Wv  = (const float*)d_in[3];
  const float* Wo  = (const float*)d_in[4];
  const float* bo  = (const float*)d_in[5];
  const int* mask_k = (const int*)d_in[6];
  const int* mask_q = (const int*)d_in[7];
  float* out = (float*)d_out;
  char* ws = (char*)d_ws;

  f16* Xh   = (f16*)(ws + OFF_XH);
  f16* Wqkv = (f16*)(ws + OFF_WQT);   // [1536][512] stacked
  f16* Wot  = (f16*)(ws + OFF_WOT);
  f16* Qh   = (f16*)(ws + OFF_QH);
  f16* Kh   = (f16*)(ws + OFF_KH);
  f16* Vt   = (f16*)(ws + OFF_VT);
  f16* A2   = (f16*)(ws + OFF_A2);

  k_cvt_x<<<2048, 256, 0, stream>>>(x, Xh);
  k_cvt_w4<<<dim3(16, 16, 4), 256, 0, stream>>>(Wq, Wk, Wv, Wo, Wqkv);

  k_gemm<3, 128><<<dim3(12, 64), 256, 0, stream>>>(Xh, Wqkv, Qh, Kh, Vt, nullptr);

  k_attn<<<dim3(32, 32), 256, 0, stream>>>(Qh, Kh, Vt, mask_k, mask_q, A2);

  k_gemm<2, 64><<<dim3(8, 64), 256, 0, stream>>>(A2, Wot, out, nullptr, nullptr, bo);
}

// Round 5
// 173.523 us; speedup vs baseline: 2.0038x; 1.2103x over previous
//
#include <hip/hip_runtime.h>

typedef _Float16 f16;
typedef _Float16 f16x8 __attribute__((ext_vector_type(8)));
typedef float    f32x4 __attribute__((ext_vector_type(4)));

#define MFMA16(A, B, C) __builtin_amdgcn_mfma_f32_16x16x32_f16((A), (B), (C), 0, 0, 0)

// async 16B global->LDS. dest = wave-uniform base + lane*16; source per-lane.
__device__ __forceinline__ void gl_lds16(const void* g, void* l) {
  __builtin_amdgcn_global_load_lds(
      (const __attribute__((address_space(1))) void*)g,
      (__attribute__((address_space(3))) void*)l, 16, 0, 0);
}

// Workspace layout (bytes).
static constexpr size_t OFF_XH  = 0;                       // X fp16 [8192][512]
static constexpr size_t OFF_WQT = 8388608;                 // QKV B^T stacked [1536][512]
static constexpr size_t OFF_WOT = OFF_WQT + 3 * 524288;
static constexpr size_t OFF_QH  = OFF_WOT + 524288;        // Q fp16 [8192][512] (pre-scaled)
static constexpr size_t OFF_KH  = OFF_QH + 8388608;        // K fp16 [8192][512]
static constexpr size_t OFF_VT  = OFF_KH + 8388608;        // V^T fp16 [4][8][64][2048]
static constexpr size_t OFF_A2  = OFF_VT + 8388608;        // attn out fp16 [8192][512]

// log2(e)*0.125 folded into Wq;  8*log2(e) subtracted via MFMA C-init.
#define QSCALE 0.18033688011112042f
#define NEGFIX -11.541560327111708f

// ---------------- convert x: fp32 -> fp16, 8 elems/thread ----------------
__global__ void k_cvt_x(const float* __restrict__ x, f16* __restrict__ xh) {
  int i = blockIdx.x * blockDim.x + threadIdx.x;
  const float4* p = (const float4*)x + (size_t)i * 2;
  float4 a = p[0], b = p[1];
  f16x8 o = { (f16)a.x, (f16)a.y, (f16)a.z, (f16)a.w,
              (f16)b.x, (f16)b.y, (f16)b.z, (f16)b.w };
  *((f16x8*)xh + i) = o;
}

// ---- transpose+convert all 4 weights (z picks which); Wq gets QSCALE folded ----
__global__ void k_cvt_w4(const float* __restrict__ w0, const float* __restrict__ w1,
                         const float* __restrict__ w2, const float* __restrict__ w3,
                         f16* __restrict__ dst) {
  __shared__ float tile[32][33];
  const int z = blockIdx.z;
  const float* w = (z == 0) ? w0 : (z == 1) ? w1 : (z == 2) ? w2 : w3;
  const float sc = (z == 0) ? QSCALE : 1.0f;
  f16* wt = dst + (size_t)z * 262144;
  int tx = threadIdx.x & 31, ty = threadIdx.x >> 5;
  int bx = blockIdx.x, by = blockIdx.y;
#pragma unroll
  for (int i = 0; i < 32; i += 8)
    tile[ty + i][tx] = w[(size_t)(by * 32 + ty + i) * 512 + bx * 32 + tx];
  __syncthreads();
#pragma unroll
  for (int i = 0; i < 32; i += 8)
    wt[(size_t)(bx * 32 + ty + i) * 512 + by * 32 + tx] = (f16)(tile[tx][ty + i] * sc);
}

// -------- 128xBN fp16 MFMA GEMM, K=512, BK=64, double-buffered LDS --------
// MODE 2: C fp32 [M][512] + bias (O0)
// MODE 3: fused QKV: col seg 0->Q fp16 (O0), 1->K fp16 (O1), 2->V^T scatter (O2)
template <int MODE, int BN>
__global__ __launch_bounds__(256, 2)
void k_gemm(const f16* __restrict__ A, const f16* __restrict__ Bt,
            void* __restrict__ O0, void* __restrict__ O1, void* __restrict__ O2,
            const float* __restrict__ bias) {
  constexpr int NF = BN / 32;
  constexpr int PB = BN / 32;
  constexpr int ABYTES = 16384;
  constexpr int BBYTES = BN * 128;
  constexpr int SM_STAGE  = 2 * (ABYTES + BBYTES);
  constexpr int SM_BOUNCE = (MODE == 3) ? 128 * 136 * 2 : 0;
  constexpr int SM = SM_STAGE > SM_BOUNCE ? SM_STAGE : SM_BOUNCE;
  __shared__ __align__(16) char smem[SM];
  const int t = threadIdx.x;
  const int lane = t & 63, w = t >> 6;
  const int wr = w >> 1, wc = w & 1;
  const int l15 = lane & 15, l4 = lane >> 4;
  const int lr = lane >> 3, lc = lane & 7;
  const int row0 = blockIdx.y * 128;
  const int col0 = blockIdx.x * BN;

  f32x4 acc[4][NF] = {};

  auto stage = [&](int kt, int buf) {
    char* dA = smem + buf * ABYTES + w * 1024;
    char* dB = smem + 2 * ABYTES + buf * BBYTES + w * 1024;
#pragma unroll
    for (int p = 0; p < 4; ++p) {
      int r = p * 32 + w * 8 + lr;
      gl_lds16((const char*)A + ((size_t)(row0 + r) * 512 + kt) * 2 + ((lc ^ (r & 7)) << 4),
               dA + p * 4096);
    }
#pragma unroll
    for (int p = 0; p < PB; ++p) {
      int r = p * 32 + w * 8 + lr;
      gl_lds16((const char*)Bt + ((size_t)(col0 + r) * 512 + kt) * 2 + ((lc ^ (r & 7)) << 4),
               dB + p * 4096);
    }
  };

  stage(0, 0);
  for (int ks = 0; ks < 8; ++ks) {
    const int buf = ks & 1;
    __syncthreads();                       // drains stage(buf); prev-buf reads done
    if (ks < 7) stage((ks + 1) * 64, buf ^ 1);  // in flight under this compute
    const char* cA = smem + buf * ABYTES;
    const char* cB = smem + 2 * ABYTES + buf * BBYTES;
    __builtin_amdgcn_s_setprio(1);
#pragma unroll
    for (int kb = 0; kb < 2; ++kb) {
      f16x8 af[4], bf[NF];
#pragma unroll
      for (int m = 0; m < 4; ++m) {
        int r = wr * 64 + m * 16 + l15;
        int lb = r * 128 + kb * 64 + l4 * 16;
        af[m] = *(const f16x8*)(cA + (lb ^ ((r & 7) << 4)));
      }
#pragma unroll
      for (int n = 0; n < NF; ++n) {
        int r = wc * (BN / 2) + n * 16 + l15;
        int lb = r * 128 + kb * 64 + l4 * 16;
        bf[n] = *(const f16x8*)(cB + (lb ^ ((r & 7) << 4)));
      }
#pragma unroll
      for (int m = 0; m < 4; ++m)
#pragma unroll
        for (int n = 0; n < NF; ++n)
          acc[m][n] = MFMA16(af[m], bf[n], acc[m][n]);
    }
    __builtin_amdgcn_s_setprio(0);
  }

  // ---- epilogue; C frag: col = lane&15, row = (lane>>4)*4 + reg ----
  if (MODE == 2) {
#pragma unroll
    for (int m = 0; m < 4; ++m)
#pragma unroll
      for (int n = 0; n < NF; ++n) {
        int gr = row0 + wr * 64 + m * 16 + l4 * 4;
        int gc = col0 + wc * (BN / 2) + n * 16 + l15;
        float* C = (float*)O0;
        float bv = bias[gc];
#pragma unroll
        for (int rr = 0; rr < 4; ++rr)
          C[(size_t)(gr + rr) * 512 + gc] = acc[m][n][rr] + bv;
      }
  } else {
    int seg = col0 >> 9;                   // block-uniform (BN=128 divides 512)
    if (seg < 2) {
      __syncthreads();
      f16* bb = (f16*)smem;                // [128][136] bounce
#pragma unroll
      for (int m = 0; m < 4; ++m)
#pragma unroll
        for (int n = 0; n < NF; ++n) {
          int r = wr * 64 + m * 16 + l4 * 4;
          int c = wc * (BN / 2) + n * 16 + l15;
#pragma unroll
          for (int rr = 0; rr < 4; ++rr)
            bb[(r + rr) * 136 + c] = (f16)acc[m][n][rr];
        }
      __syncthreads();
      f16* C = (f16*)(seg == 0 ? O0 : O1);
      int cbase = col0 & 511;
#pragma unroll
      for (int i = 0; i < 8; ++i) {
        int idx = i * 256 + t;
        int r = idx >> 4, c8 = (idx & 15) * 8;
        uint4 v = *(const uint4*)(bb + r * 136 + c8);
        *(uint4*)(C + (size_t)(row0 + r) * 512 + cbase + c8) = v;
      }
    } else {
#pragma unroll
      for (int m = 0; m < 4; ++m)
#pragma unroll
        for (int n = 0; n < NF; ++n) {
          int gr = row0 + wr * 64 + m * 16 + l4 * 4;
          int lcol = (col0 & 511) + wc * (BN / 2) + n * 16 + l15;
          f16* C = (f16*)O2;
          int hh = lcol >> 6, dd = lcol & 63;
          int bb2 = gr >> 11, ns = gr & 2047;
          union { uint2 u2; f16 v[4]; } pk;
#pragma unroll
          for (int rr = 0; rr < 4; ++rr) pk.v[rr] = (f16)acc[m][n][rr];
          *(uint2*)(C + (size_t)((bb2 * 8 + hh) * 64 + dd) * 2048 + ns) = pk.u2;
        }
    }
  }
}

// ------------- flash attention: fixed-max softmax, denom via MFMA -------------
// 4 waves x 32 q-rows (QBLK=128); K/V frags read once, reused by 2 A-frags.
// sP swizzled 128B rows (conflict-free b16 writes + b128 A-frag reads).
__global__ __launch_bounds__(256, 3)
void k_attn(const f16* __restrict__ Q, const f16* __restrict__ K,
            const f16* __restrict__ Vt, const int* __restrict__ mask_k,
            const int* __restrict__ mask_q, f16* __restrict__ A2) {
  __shared__ __align__(16) f16 sK[2][64 * 64];      // [j][d], swizzled
  __shared__ __align__(16) f16 sV[2][64 * 64];      // [d][j], swizzled
  __shared__ __align__(16) f16 sP[4][32 * 64];      // per-wave [32 q][64 k], swizzled
  const int t = threadIdx.x, lane = t & 63, w = t >> 6;
  const int l15 = lane & 15, l4 = lane >> 4;
  const int lr = lane >> 3, lc = lane & 7;
  const int bh = blockIdx.y, b = bh >> 3, h = bh & 7;
  const int q0 = blockIdx.x * 128 + w * 32;

  f16x8 qa[2][2];
  int mqi[2][4];
#pragma unroll
  for (int g = 0; g < 2; ++g) {
    const f16* qb = Q + (size_t)(b * 2048 + q0 + g * 16 + l15) * 512 + h * 64 + l4 * 8;
    qa[g][0] = *(const f16x8*)qb;
    qa[g][1] = *(const f16x8*)(qb + 32);
#pragma unroll
    for (int rr = 0; rr < 4; ++rr)
      mqi[g][rr] = mask_q[b * 2048 + q0 + g * 16 + l4 * 4 + rr];
  }

  const f16x8 onesv = { (f16)1.f, (f16)1.f, (f16)1.f, (f16)1.f,
                        (f16)1.f, (f16)1.f, (f16)1.f, (f16)1.f };
  f32x4 o[2][4] = {};
  f32x4 oex[2] = {};

  const char* Kbase  = (const char*)K + ((size_t)b * 2048 * 512 + h * 64) * 2;
  const char* VtBase = (const char*)Vt + ((size_t)(b * 8 + h) * 64) * 2048 * 2;
  char* sPw = (char*)&sP[w][0];

  auto stage = [&](int kv, int buf) {
#pragma unroll
    for (int p = 0; p < 2; ++p) {
      int r = p * 32 + w * 8 + lr;
      gl_lds16(Kbase + (size_t)(kv + r) * 1024 + ((lc ^ (r & 7)) << 4),
               (char*)&sK[buf][0] + p * 4096 + w * 1024);
      gl_lds16(VtBase + ((size_t)r * 2048 + kv) * 2 + ((lc ^ (r & 7)) << 4),
               (char*)&sV[buf][0] + p * 4096 + w * 1024);
    }
  };

  stage(0, 0);
  for (int it = 0; it < 32; ++it) {
    const int kv = it * 64, buf = it & 1;
    __syncthreads();                       // buf ready; buf^1 reads done
    if (it < 31) stage(kv + 64, buf ^ 1);  // hides under this tile's compute

    int mk[4];
#pragma unroll
    for (int jf = 0; jf < 4; ++jf)
      mk[jf] = mask_k[b * 2048 + kv + jf * 16 + l15];

    // S = Q K^T + NEGFIX ; K frags read once, used by both q-groups
    f32x4 s[2][4];
    __builtin_amdgcn_s_setprio(1);
#pragma unroll
    for (int jf = 0; jf < 4; ++jf) {
      int r = jf * 16 + l15;
      int base = r * 128 + l4 * 16;
      f16x8 b0 = *(const f16x8*)((const char*)&sK[buf][0] + (base ^ ((r & 7) << 4)));
      f16x8 b1 = *(const f16x8*)((const char*)&sK[buf][0] + ((base + 64) ^ ((r & 7) << 4)));
#pragma unroll
      for (int g = 0; g < 2; ++g) {
        f32x4 z = { NEGFIX, NEGFIX, NEGFIX, NEGFIX };
        z = MFMA16(qa[g][0], b0, z);
        z = MFMA16(qa[g][1], b1, z);
        s[g][jf] = z;
      }
    }
    __builtin_amdgcn_s_setprio(0);

    // fixed-max numerator: p = exp2(masked s) -> swizzled sP
#pragma unroll
    for (int g = 0; g < 2; ++g)
#pragma unroll
      for (int jf = 0; jf < 4; ++jf)
#pragma unroll
        for (int rr = 0; rr < 4; ++rr) {
          float sv = s[g][jf][rr];
          sv = mk[jf] ? sv : -1000.0f;     // masked key -> p = 0
          sv = mqi[g][rr] ? sv : -8.0f;    // masked q row -> uniform p
          float p = __builtin_amdgcn_exp2f(sv);
          int row = g * 16 + l4 * 4 + rr;
          int boff = row * 128 + (jf * 16 + l15) * 2;
          *(f16*)(sPw + (boff ^ ((row & 7) << 4))) = (f16)p;
        }

    // O += P V ; denom += P 1 ; V frags read once, used by both q-groups
    __builtin_amdgcn_s_setprio(1);
#pragma unroll
    for (int kb = 0; kb < 2; ++kb) {
      f16x8 pa[2];
#pragma unroll
      for (int g = 0; g < 2; ++g) {
        int r = g * 16 + l15;
        int base = r * 128 + kb * 64 + l4 * 16;
        pa[g] = *(const f16x8*)(sPw + (base ^ ((r & 7) << 4)));
        oex[g] = MFMA16(pa[g], onesv, oex[g]);
      }
#pragma unroll
      for (int df = 0; df < 4; ++df) {
        int r = df * 16 + l15;
        int base = r * 128 + kb * 64 + l4 * 16;
        f16x8 bv = *(const f16x8*)((const char*)&sV[buf][0] + (base ^ ((r & 7) << 4)));
#pragma unroll
        for (int g = 0; g < 2; ++g)
          o[g][df] = MFMA16(pa[g], bv, o[g][df]);
      }
    }
    __builtin_amdgcn_s_setprio(0);
  }

#pragma unroll
  for (int g = 0; g < 2; ++g) {
    float inv[4];
#pragma unroll
    for (int rr = 0; rr < 4; ++rr) inv[rr] = 1.0f / oex[g][rr];
#pragma unroll
    for (int df = 0; df < 4; ++df)
#pragma unroll
      for (int rr = 0; rr < 4; ++rr)
        A2[(size_t)(b * 2048 + q0 + g * 16 + l4 * 4 + rr) * 512 + h * 64 + df * 16 + l15] =
            (f16)(o[g][df][rr] * inv[rr]);
  }
}

extern "C" void kernel_launch(void* const* d_in, const int* in_sizes, int n_in,
                              void* d_out, int out_size, void* d_ws, size_t ws_size,
                              hipStream_t stream) {
  (void)in_sizes; (void)n_in; (void)out_size; (void)ws_size;
  const float* x   = (const float*)d_in[0];
  const float* Wq  = (const float*)d_in[1];
  const float* Wk  = (const float*)d_in[2];
  const float* Wv  = (const float*)d_in[3];
  const float* Wo  = (const float*)d_in[4];
  const float* bo  = (const float*)d_in[5];
  const int* mask_k = (const int*)d_in[6];
  const int* mask_q = (const int*)d_in[7];
  float* out = (float*)d_out;
  char* ws = (char*)d_ws;

  f16* Xh   = (f16*)(ws + OFF_XH);
  f16* Wqkv = (f16*)(ws + OFF_WQT);
  f16* Wot  = (f16*)(ws + OFF_WOT);
  f16* Qh   = (f16*)(ws + OFF_QH);
  f16* Kh   = (f16*)(ws + OFF_KH);
  f16* Vt   = (f16*)(ws + OFF_VT);
  f16* A2   = (f16*)(ws + OFF_A2);

  k_cvt_x<<<2048, 256, 0, stream>>>(x, Xh);
  k_cvt_w4<<<dim3(16, 16, 4), 256, 0, stream>>>(Wq, Wk, Wv, Wo, Wqkv);

  k_gemm<3, 128><<<dim3(12, 64), 256, 0, stream>>>(Xh, Wqkv, Qh, Kh, Vt, nullptr);

  k_attn<<<dim3(16, 32), 256, 0, stream>>>(Qh, Kh, Vt, mask_k, mask_q, A2);

  k_gemm<2, 128><<<dim3(4, 64), 256, 0, stream>>>(A2, Wot, out, nullptr, nullptr, bo);
}

// Round 8
// 158.749 us; speedup vs baseline: 2.1903x; 1.0931x over previous
//
#include <hip/hip_runtime.h>

typedef _Float16 f16;
typedef __fp16   fp16x2 __attribute__((ext_vector_type(2)));   // cvt_pkrtz return type
typedef _Float16 f16x8 __attribute__((ext_vector_type(8)));
typedef float    f32x4 __attribute__((ext_vector_type(4)));

#define MFMA16(A, B, C) __builtin_amdgcn_mfma_f32_16x16x32_f16((A), (B), (C), 0, 0, 0)

// async 16B global->LDS. dest = wave-uniform base + lane*16; source per-lane.
__device__ __forceinline__ void gl_lds16(const void* g, void* l) {
  __builtin_amdgcn_global_load_lds(
      (const __attribute__((address_space(1))) void*)g,
      (__attribute__((address_space(3))) void*)l, 16, 0, 0);
}

// Workspace layout (bytes).
static constexpr size_t OFF_XH  = 0;                       // X fp16 [8192][512]
static constexpr size_t OFF_WQT = 8388608;                 // QKV B^T stacked [1536][512]
static constexpr size_t OFF_WOT = OFF_WQT + 3 * 524288;
static constexpr size_t OFF_QH  = OFF_WOT + 524288;        // Q fp16 [8192][512] (pre-scaled)
static constexpr size_t OFF_KH  = OFF_QH + 8388608;        // K fp16 [8192][512]
static constexpr size_t OFF_VT  = OFF_KH + 8388608;        // V^T fp16 [4][8][64][2048]
static constexpr size_t OFF_A2  = OFF_VT + 8388608;        // attn out fp16 [8192][512]
static constexpr size_t OFF_AMK = OFF_A2 + 8388608;        // add-mask f32 [4][2048]

// log2(e)*0.125 folded into Wq;  8*log2(e) subtracted via MFMA C-init.
#define QSCALE 0.18033688011112042f
#define NEGFIX -11.541560327111708f

// -------- convert x: fp32 -> fp16; also build additive k-mask array --------
__global__ void k_cvt_x(const float* __restrict__ x, f16* __restrict__ xh,
                        const int* __restrict__ mask_k, float* __restrict__ amk) {
  int i = blockIdx.x * blockDim.x + threadIdx.x;
  const float4* p = (const float4*)x + (size_t)i * 2;
  float4 a = p[0], b = p[1];
  f16x8 o = { (f16)a.x, (f16)a.y, (f16)a.z, (f16)a.w,
              (f16)b.x, (f16)b.y, (f16)b.z, (f16)b.w };
  *((f16x8*)xh + i) = o;
  if (i < 8192) amk[i] = mask_k[i] ? 0.0f : -1000.0f;
}

// ---- transpose+convert all 4 weights (z picks which); Wq gets QSCALE folded ----
__global__ void k_cvt_w4(const float* __restrict__ w0, const float* __restrict__ w1,
                         const float* __restrict__ w2, const float* __restrict__ w3,
                         f16* __restrict__ dst) {
  __shared__ float tile[32][33];
  const int z = blockIdx.z;
  const float* w = (z == 0) ? w0 : (z == 1) ? w1 : (z == 2) ? w2 : w3;
  const float sc = (z == 0) ? QSCALE : 1.0f;
  f16* wt = dst + (size_t)z * 262144;
  int tx = threadIdx.x & 31, ty = threadIdx.x >> 5;
  int bx = blockIdx.x, by = blockIdx.y;
#pragma unroll
  for (int i = 0; i < 32; i += 8)
    tile[ty + i][tx] = w[(size_t)(by * 32 + ty + i) * 512 + bx * 32 + tx];
  __syncthreads();
#pragma unroll
  for (int i = 0; i < 32; i += 8)
    wt[(size_t)(bx * 32 + ty + i) * 512 + by * 32 + tx] = (f16)(tile[tx][ty + i] * sc);
}

// -------- BMxBN fp16 MFMA GEMM, K=512, BK=64, double-buffered, XCD-swizzled ------
// MODE 2: C fp32 [M][512] + bias (O0)
// MODE 3: fused QKV (BM=BN=128): seg 0->Q f16 (O0), 1->K f16 (O1), 2->V^T (O2)
template <int MODE, int BM, int BN>
__global__ __launch_bounds__(256, (MODE == 2 ? 3 : 2))
void k_gemm(const f16* __restrict__ A, const f16* __restrict__ Bt,
            void* __restrict__ O0, void* __restrict__ O1, void* __restrict__ O2,
            const float* __restrict__ bias) {
  constexpr int MR = BM / 32, NF = BN / 32;
  constexpr int AP = BM / 32, BP = BN / 32;       // 4KB stage issues
  constexpr int ABYTES = BM * 128;
  constexpr int BBYTES = BN * 128;
  constexpr int SM_STAGE  = 2 * (ABYTES + BBYTES);
  constexpr int SM_BOUNCE = (MODE == 3) ? 128 * 136 * 2 : 0;
  constexpr int SM = SM_STAGE > SM_BOUNCE ? SM_STAGE : SM_BOUNCE;
  __shared__ __align__(16) char smem[SM];
  const int t = threadIdx.x;
  const int lane = t & 63, w = t >> 6;
  const int wr = w >> 1, wc = w & 1;
  const int l15 = lane & 15, l4 = lane >> 4;
  const int lr = lane >> 3, lc = lane & 7;
  // XCD-bijective swizzle (grid %8 == 0): contiguous work chunk per XCD
  const int flat = blockIdx.x + gridDim.x * blockIdx.y;
  const int nwg  = gridDim.x * gridDim.y;
  const int sw   = (flat & 7) * (nwg >> 3) + (flat >> 3);
  const int row0 = (sw / gridDim.x) * BM;
  const int col0 = (sw % gridDim.x) * BN;

  f32x4 acc[MR][NF] = {};

  auto stage = [&](int kt, int buf) {
    char* dA = smem + buf * ABYTES + w * 1024;
    char* dB = smem + 2 * ABYTES + buf * BBYTES + w * 1024;
#pragma unroll
    for (int p = 0; p < AP; ++p) {
      int r = p * 32 + w * 8 + lr;
      gl_lds16((const char*)A + ((size_t)(row0 + r) * 512 + kt) * 2 + ((lc ^ (r & 7)) << 4),
               dA + p * 4096);
    }
#pragma unroll
    for (int p = 0; p < BP; ++p) {
      int r = p * 32 + w * 8 + lr;
      gl_lds16((const char*)Bt + ((size_t)(col0 + r) * 512 + kt) * 2 + ((lc ^ (r & 7)) << 4),
               dB + p * 4096);
    }
  };

  stage(0, 0);
  for (int ks = 0; ks < 8; ++ks) {
    const int buf = ks & 1;
    __syncthreads();                            // stage(buf) drained; buf^1 reads done
    if (ks < 7) stage((ks + 1) * 64, buf ^ 1);  // in flight under this compute
    const char* cA = smem + buf * ABYTES;
    const char* cB = smem + 2 * ABYTES + buf * BBYTES;
    __builtin_amdgcn_s_setprio(1);
#pragma unroll
    for (int kb = 0; kb < 2; ++kb) {
      f16x8 af[MR], bf[NF];
#pragma unroll
      for (int m = 0; m < MR; ++m) {
        int r = wr * (BM / 2) + m * 16 + l15;
        int lb = r * 128 + kb * 64 + l4 * 16;
        af[m] = *(const f16x8*)(cA + (lb ^ ((r & 7) << 4)));
      }
#pragma unroll
      for (int n = 0; n < NF; ++n) {
        int r = wc * (BN / 2) + n * 16 + l15;
        int lb = r * 128 + kb * 64 + l4 * 16;
        bf[n] = *(const f16x8*)(cB + (lb ^ ((r & 7) << 4)));
      }
#pragma unroll
      for (int m = 0; m < MR; ++m)
#pragma unroll
        for (int n = 0; n < NF; ++n)
          acc[m][n] = MFMA16(af[m], bf[n], acc[m][n]);
    }
    __builtin_amdgcn_s_setprio(0);
  }

  // ---- epilogue; C frag: col = lane&15, row = (lane>>4)*4 + reg ----
  if (MODE == 2) {
#pragma unroll
    for (int m = 0; m < MR; ++m)
#pragma unroll
      for (int n = 0; n < NF; ++n) {
        int gr = row0 + wr * (BM / 2) + m * 16 + l4 * 4;
        int gc = col0 + wc * (BN / 2) + n * 16 + l15;
        float* C = (float*)O0;
        float bv = bias[gc];
#pragma unroll
        for (int rr = 0; rr < 4; ++rr)
          C[(size_t)(gr + rr) * 512 + gc] = acc[m][n][rr] + bv;
      }
  } else {
    int seg = col0 >> 9;                        // block-uniform
    if (seg < 2) {
      __syncthreads();
      f16* bb = (f16*)smem;                     // [128][136] bounce
#pragma unroll
      for (int m = 0; m < MR; ++m)
#pragma unroll
        for (int n = 0; n < NF; ++n) {
          int r = wr * (BM / 2) + m * 16 + l4 * 4;
          int c = wc * (BN / 2) + n * 16 + l15;
#pragma unroll
          for (int rr = 0; rr < 4; ++rr)
            bb[(r + rr) * 136 + c] = (f16)acc[m][n][rr];
        }
      __syncthreads();
      f16* C = (f16*)(seg == 0 ? O0 : O1);
      int cbase = col0 & 511;
#pragma unroll
      for (int i = 0; i < 8; ++i) {
        int idx = i * 256 + t;
        int r = idx >> 4, c8 = (idx & 15) * 8;
        uint4 v = *(const uint4*)(bb + r * 136 + c8);
        *(uint4*)(C + (size_t)(row0 + r) * 512 + cbase + c8) = v;
      }
    } else {
#pragma unroll
      for (int m = 0; m < MR; ++m)
#pragma unroll
        for (int n = 0; n < NF; ++n) {
          int gr = row0 + wr * (BM / 2) + m * 16 + l4 * 4;
          int lcol = (col0 & 511) + wc * (BN / 2) + n * 16 + l15;
          f16* C = (f16*)O2;
          int hh = lcol >> 6, dd = lcol & 63;
          int bb2 = gr >> 11, ns = gr & 2047;
          union { uint2 u2; f16 v[4]; } pk;
#pragma unroll
          for (int rr = 0; rr < 4; ++rr) pk.v[rr] = (f16)acc[m][n][rr];
          *(uint2*)(C + (size_t)((bb2 * 8 + hh) * 64 + dd) * 2048 + ns) = pk.u2;
        }
    }
  }
}

// ------------- flash attention: swapped QK^T, fixed-max, denom via MFMA -------------
// 4 waves x 32 q; KVBLK=128 (2 sub-halves, ONE barrier/tile). S^T = mfma(K,Q) so a
// lane's 4 regs are j-adjacent -> cvt_pkrtz pack -> one ds_write_b64 per (g,jf).
// Masks: additive f32 amk (0/-1000) + per-q (qm,qoff) folded into 2 FMAs.
__global__ __launch_bounds__(256, 2)
void k_attn(const f16* __restrict__ Q, const f16* __restrict__ K,
            const f16* __restrict__ Vt, const float* __restrict__ amk,
            const int* __restrict__ mask_q, f16* __restrict__ A2) {
  __shared__ __align__(16) f16 sK[2][128 * 64];     // [j][d] 128B rows, swizzled
  __shared__ __align__(16) f16 sV[2][64 * 128];     // [d][j] 256B rows, swizzled
  __shared__ __align__(16) f16 sP[4][32 * 64];      // per-wave [q][j], swizzled
  const int t = threadIdx.x, lane = t & 63, w = t >> 6;
  const int l15 = lane & 15, l4 = lane >> 4;
  const int lr = lane >> 3, lc = lane & 7;
  // XCD swizzle: 16 q-blocks of one (b,h) contiguous per XCD chunk
  const int sw = (blockIdx.x & 7) * 64 + (blockIdx.x >> 3);
  const int qx = sw & 15, bh = sw >> 4;
  const int b = bh >> 3, h = bh & 7;
  const int q0 = qx * 128 + w * 32;

  f16x8 qa[2][2];
  float qm[2], qo[2];
#pragma unroll
  for (int g = 0; g < 2; ++g) {
    const f16* qb = Q + (size_t)(b * 2048 + q0 + g * 16 + l15) * 512 + h * 64 + l4 * 8;
    qa[g][0] = *(const f16x8*)qb;
    qa[g][1] = *(const f16x8*)(qb + 32);
    int mq = mask_q[b * 2048 + q0 + g * 16 + l15];
    qm[g] = mq ? 1.0f : 0.0f;
    qo[g] = mq ? 0.0f : -8.0f;
  }

  const f16x8 onesv = { (f16)1.f, (f16)1.f, (f16)1.f, (f16)1.f,
                        (f16)1.f, (f16)1.f, (f16)1.f, (f16)1.f };
  f32x4 o[2][4] = {};
  f32x4 oex[2] = {};

  const char* Kbase  = (const char*)K + ((size_t)b * 2048 * 512 + h * 64) * 2;
  const char* VtBase = (const char*)Vt + ((size_t)(b * 8 + h) * 64) * 2048 * 2;
  const float* amkb = amk + b * 2048;
  char* sPw = (char*)&sP[w][0];

  auto stage = [&](int kv, int buf) {
#pragma unroll
    for (int p = 0; p < 4; ++p) {                   // K: 128 rows x 128B
      int r = p * 32 + w * 8 + lr;
      gl_lds16(Kbase + (size_t)(kv + r) * 1024 + ((lc ^ (r & 7)) << 4),
               (char*)&sK[buf][0] + p * 4096 + w * 1024);
    }
#pragma unroll
    for (int p = 0; p < 4; ++p) {                   // V^T: 64 rows x 256B
      int d = p * 16 + w * 4 + (lane >> 4);
      int c = lane & 15;
      gl_lds16(VtBase + ((size_t)d * 2048 + kv) * 2 + ((c ^ (d & 7)) << 4),
               (char*)&sV[buf][0] + p * 4096 + w * 1024);
    }
  };

  stage(0, 0);
  for (int it = 0; it < 16; ++it) {
    const int kv = it * 128, buf = it & 1;
    __syncthreads();                                // buf ready; buf^1 reads done
    if (it < 15) stage(kv + 128, buf ^ 1);          // hides under 2 half-tiles
    const char* cK = (const char*)&sK[buf][0];
    const char* cV = (const char*)&sV[buf][0];

#pragma unroll
    for (int h2 = 0; h2 < 2; ++h2) {
      // S^T = K Q^T + NEGFIX: rows j, cols q (swapped operands)
      f32x4 sT[2][4];
      __builtin_amdgcn_s_setprio(1);
#pragma unroll
      for (int jf = 0; jf < 4; ++jf) {
        int r = h2 * 64 + jf * 16 + l15;
        int base = r * 128 + l4 * 16;
        f16x8 k0 = *(const f16x8*)(cK + (base ^ ((r & 7) << 4)));
        f16x8 k1 = *(const f16x8*)(cK + ((base + 64) ^ ((r & 7) << 4)));
#pragma unroll
        for (int g = 0; g < 2; ++g) {
          f32x4 z = { NEGFIX, NEGFIX, NEGFIX, NEGFIX };
          z = MFMA16(k0, qa[g][0], z);
          z = MFMA16(k1, qa[g][1], z);
          sT[g][jf] = z;
        }
      }
      __builtin_amdgcn_s_setprio(0);

      // mask(2 FMA) + exp2 + pack -> one b64 write per (g,jf)
      f32x4 amv[4];
#pragma unroll
      for (int jf = 0; jf < 4; ++jf)
        amv[jf] = *(const f32x4*)(amkb + kv + h2 * 64 + jf * 16 + l4 * 4);
#pragma unroll
      for (int g = 0; g < 2; ++g)
#pragma unroll
        for (int jf = 0; jf < 4; ++jf) {
          float p0 = __builtin_amdgcn_exp2f(
              __builtin_fmaf(amv[jf][0], qm[g],
                  __builtin_fmaf(sT[g][jf][0], qm[g], qo[g])));
          float p1 = __builtin_amdgcn_exp2f(
              __builtin_fmaf(amv[jf][1], qm[g],
                  __builtin_fmaf(sT[g][jf][1], qm[g], qo[g])));
          float p2 = __builtin_amdgcn_exp2f(
              __builtin_fmaf(amv[jf][2], qm[g],
                  __builtin_fmaf(sT[g][jf][2], qm[g], qo[g])));
          float p3 = __builtin_amdgcn_exp2f(
              __builtin_fmaf(amv[jf][3], qm[g],
                  __builtin_fmaf(sT[g][jf][3], qm[g], qo[g])));
          fp16x2 a01 = __builtin_amdgcn_cvt_pkrtz(p0, p1);
          fp16x2 a23 = __builtin_amdgcn_cvt_pkrtz(p2, p3);
          uint2 pk = { __builtin_bit_cast(unsigned, a01),
                       __builtin_bit_cast(unsigned, a23) };
          int row = g * 16 + l15;
          int boff = row * 128 + jf * 32 + l4 * 8;
          *(uint2*)(sPw + (boff ^ ((row & 7) << 4))) = pk;
        }

      // O += P V ; denom += P 1
      __builtin_amdgcn_s_setprio(1);
#pragma unroll
      for (int kb = 0; kb < 2; ++kb) {
        f16x8 pa[2];
#pragma unroll
        for (int g = 0; g < 2; ++g) {
          int rq = g * 16 + l15;
          int pbase = rq * 128 + kb * 64 + l4 * 16;
          pa[g] = *(const f16x8*)(sPw + (pbase ^ ((rq & 7) << 4)));
          oex[g] = MFMA16(pa[g], onesv, oex[g]);
        }
#pragma unroll
        for (int df = 0; df < 4; ++df) {
          int d = df * 16 + l15;
          int vbase = d * 256 + h2 * 128 + kb * 64 + l4 * 16;
          f16x8 bv = *(const f16x8*)(cV + (vbase ^ ((d & 7) << 4)));
#pragma unroll
          for (int g = 0; g < 2; ++g)
            o[g][df] = MFMA16(pa[g], bv, o[g][df]);
        }
      }
      __builtin_amdgcn_s_setprio(0);
    }
  }

#pragma unroll
  for (int g = 0; g < 2; ++g) {
    float inv[4];
#pragma unroll
    for (int rr = 0; rr < 4; ++rr) inv[rr] = 1.0f / oex[g][rr];
#pragma unroll
    for (int df = 0; df < 4; ++df)
#pragma unroll
      for (int rr = 0; rr < 4; ++rr)
        A2[(size_t)(b * 2048 + q0 + g * 16 + l4 * 4 + rr) * 512 + h * 64 + df * 16 + l15] =
            (f16)(o[g][df][rr] * inv[rr]);
  }
}

extern "C" void kernel_launch(void* const* d_in, const int* in_sizes, int n_in,
                              void* d_out, int out_size, void* d_ws, size_t ws_size,
                              hipStream_t stream) {
  (void)in_sizes; (void)n_in; (void)out_size; (void)ws_size;
  const float* x   = (const float*)d_in[0];
  const float* Wq  = (const float*)d_in[1];
  const float* Wk  = (const float*)d_in[2];
  const float* Wv  = (const float*)d_in[3];
  const float* Wo  = (const float*)d_in[4];
  const float* bo  = (const float*)d_in[5];
  const int* mask_k = (const int*)d_in[6];
  const int* mask_q = (const int*)d_in[7];
  float* out = (float*)d_out;
  char* ws = (char*)d_ws;

  f16* Xh   = (f16*)(ws + OFF_XH);
  f16* Wqkv = (f16*)(ws + OFF_WQT);
  f16* Wot  = (f16*)(ws + OFF_WOT);
  f16* Qh   = (f16*)(ws + OFF_QH);
  f16* Kh   = (f16*)(ws + OFF_KH);
  f16* Vt   = (f16*)(ws + OFF_VT);
  f16* A2   = (f16*)(ws + OFF_A2);
  float* AMK = (float*)(ws + OFF_AMK);

  k_cvt_x<<<2048, 256, 0, stream>>>(x, Xh, mask_k, AMK);
  k_cvt_w4<<<dim3(16, 16, 4), 256, 0, stream>>>(Wq, Wk, Wv, Wo, Wqkv);

  k_gemm<3, 128, 128><<<dim3(12, 64), 256, 0, stream>>>(Xh, Wqkv, Qh, Kh, Vt, nullptr);

  k_attn<<<512, 256, 0, stream>>>(Qh, Kh, Vt, AMK, mask_q, A2);

  k_gemm<2, 128, 64><<<dim3(8, 64), 256, 0, stream>>>(A2, Wot, out, nullptr, nullptr, bo);
}